// Round 10
// baseline (29.617 us; speedup 1.0000x reference)
//
#include <hip/hip_runtime.h>
#include <hip/hip_fp16.h>

// SurfEval: B=8, M=128, N=128, ctrl 4ch, P=Q=3, OUT=512
// ctrl_pts : (8,128,128,4) f32; Nu/Nv: (512,512,4) f32; spans: (512,512) i32 in [3,127]
// out : (8,512,512,3) f32 = sw[...,:3]/sw[...,3:]
//
// Round-10: one batch's whole control net (128x128 half4 = 128 KB) lives in
// LDS; the random patch gather becomes ds_read_b64 with imm offsets. All
// global accesses are contiguous streams. Grid = 8 batches x 32 uv-chunks
// = 256 blocks (1/CU, LDS-bound), 1024 threads, 8 uv-iterations each.

#define OUTD 512
#define UVN  (OUTD * OUTD)   // 262144
#define MD   128
#define ND   128
#define BD   8
#define TPB   1024
#define CHUNKS 32
#define UVPB  (UVN / CHUNKS)          // 8192 uv per block
#define ITERS (UVPB / TPB)            // 8

__global__ __launch_bounds__(TPB) void surfeval_lds_kernel(
    const float4* __restrict__ ctrl,   // (b, m*n) float4
    const float4* __restrict__ Nu4,
    const float4* __restrict__ Nv4,
    const int* __restrict__ uspan,
    const int* __restrict__ vspan,
    float* __restrict__ out)
{
    __shared__ uint2 cl[MD * ND];        // 128 KB: half4 per (m,n), this block's batch
    __shared__ float rs[TPB * 3];        // 12 KB: store-shuffle buffer

    const int b     = blockIdx.x >> 5;   // 8 batches
    const int chunk = blockIdx.x & 31;   // 32 uv chunks
    const int tid   = threadIdx.x;

    // ---- stage batch b: 256 KB f32 -> 128 KB fp16 LDS (fully coalesced) ----
    const float4* cb = ctrl + b * (MD * ND);
    #pragma unroll
    for (int i = 0; i < (MD * ND) / TPB; ++i) {   // 16 iterations
        const int idx = i * TPB + tid;
        const float4 c = cb[idx];
        __half2 h01 = __floats2half2_rn(c.x, c.y);
        __half2 h23 = __floats2half2_rn(c.z, c.w);
        uint2 u;
        u.x = *reinterpret_cast<unsigned int*>(&h01);
        u.y = *reinterpret_cast<unsigned int*>(&h23);
        cl[idx] = u;                               // consecutive 8B -> conflict-free
    }
    __syncthreads();

    const char* ldsb = (const char*)cl;

    for (int it = 0; it < ITERS; ++it) {
        const int uvbase = chunk * UVPB + it * TPB;
        const int uv = uvbase + tid;

        // all lane-consecutive loads: 1 request per line
        const int us3 = uspan[uv] - 3;
        const int vs3 = vspan[uv] - 3;
        const float4 nu = Nu4[uv];
        const float4 nv = Nv4[uv];
        const float nuL[4] = {nu.x, nu.y, nu.z, nu.w};
        const float nvL[4] = {nv.x, nv.y, nv.z, nv.w};

        // patch gather from LDS: byte = ((us3+l)*128 + vs3+r)*8
        const int base = (us3 * ND + vs3) * 8;
        float ax = 0.f, ay = 0.f, az = 0.f, aw = 0.f;
        #pragma unroll
        for (int l = 0; l < 4; ++l) {
            #pragma unroll
            for (int r = 0; r < 4; ++r) {
                const uint2 h = *(const uint2*)(ldsb + base + l * (ND * 8) + r * 8);
                const float w = nuL[l] * nvL[r];
                const float2 xy = __half22float2(*(const __half2*)(&h.x));
                const float2 zw = __half22float2(*(const __half2*)(&h.y));
                ax = fmaf(w, xy.x, ax);
                ay = fmaf(w, xy.y, ay);
                az = fmaf(w, zw.x, az);
                aw = fmaf(w, zw.y, aw);
            }
        }
        const float inv = 1.0f / aw;

        // ---- store shuffle: rs then fully-coalesced float4 stores ----
        __syncthreads();                  // prior iter's readers are done
        rs[tid * 3 + 0] = ax * inv;       // stride-3 dwords: 2-way banks, free
        rs[tid * 3 + 1] = ay * inv;
        rs[tid * 3 + 2] = az * inv;
        __syncthreads();

        float* dst = out + ((size_t)b * UVN + uvbase) * 3;
        #pragma unroll
        for (int k = tid; k < (TPB * 3) / 4; k += TPB)   // 768 float4
            reinterpret_cast<float4*>(dst)[k] =
                reinterpret_cast<const float4*>(rs)[k];
    }
}

extern "C" void kernel_launch(void* const* d_in, const int* in_sizes, int n_in,
                              void* d_out, int out_size, void* d_ws, size_t ws_size,
                              hipStream_t stream) {
    const float* ctrl  = (const float*)d_in[0];
    const float* Nu    = (const float*)d_in[1];
    const float* Nv    = (const float*)d_in[2];
    const int*   uspan = (const int*)d_in[3];
    const int*   vspan = (const int*)d_in[4];
    float* out = (float*)d_out;

    surfeval_lds_kernel<<<BD * CHUNKS, TPB, 0, stream>>>(
        (const float4*)ctrl, (const float4*)Nu, (const float4*)Nv,
        uspan, vspan, out);
}

// Round 11
// 29.524 us; speedup vs baseline: 1.0032x; 1.0032x over previous
//
#include <hip/hip_runtime.h>
#include <hip/hip_fp16.h>

// SurfEval: B=8, M=128, N=128, ctrl 4ch, P=Q=3, OUT=512
// ctrl_pts : (8,128,128,4) f32; Nu/Nv: (512,512,4) f32; spans: (512,512) i32 in [3,127]
// out : (8,512,512,3) f32 = sw[...,:3]/sw[...,3:]
//
// Round-11: one batch (128x128 half4 = 128 KB fp16) in LDS per block.
// Grid 256 = 32 uv-chunks x 8 batches; same-chunk blocks share an XCD
// (bid mod 8 = chunk low bits) so the packed per-uv stream {spans, fp16
// Nu, fp16 Nv} is HBM-read once and L2-hit by the other 7 blocks.
// No per-iteration barriers; all global accesses dense.

#define OUTD 512
#define UVN  (OUTD * OUTD)   // 262144
#define MD   128
#define ND   128
#define BD   8
#define MN   (MD * ND)       // 16384
#define TPB  1024
#define NCHUNK 32
#define UVPC (UVN / NCHUNK)  // 8192
#define ITERS (UVPC / TPB)   // 8

__device__ __forceinline__ ushort4 cvt4h(const float4 c) {
    ushort4 h;
    h.x = __half_as_ushort(__float2half(c.x));
    h.y = __half_as_ushort(__float2half(c.y));
    h.z = __half_as_ushort(__float2half(c.z));
    h.w = __half_as_ushort(__float2half(c.w));
    return h;
}

__device__ __forceinline__ uint2 pack4h(const float4 c) {
    __half2 h01 = __floats2half2_rn(c.x, c.y);
    __half2 h23 = __floats2half2_rn(c.z, c.w);
    uint2 u;
    u.x = *reinterpret_cast<unsigned int*>(&h01);
    u.y = *reinterpret_cast<unsigned int*>(&h23);
    return u;
}

// ---------- prep: fp16 convert of ctrl (planar, no transpose) + packed stream ----------
__global__ __launch_bounds__(256) void prep11_kernel(
    const float4* __restrict__ ctrl, uint2* __restrict__ ctrlP,
    const float4* __restrict__ Nu4, const float4* __restrict__ Nv4,
    const int* __restrict__ uspan, const int* __restrict__ vspan,
    unsigned int* __restrict__ spk, uint2* __restrict__ nuh, uint2* __restrict__ nvh)
{
    const int t = blockIdx.x * 256 + threadIdx.x;
    if (t < BD * MN) {                       // blocks 0..511: dense f32->fp16
        ctrlP[t] = pack4h(ctrl[t]);
        return;
    }
    const int uv = t - BD * MN;              // blocks 512..1535: pack stream
    spk[uv] = (unsigned int)(uspan[uv] - 3) | ((unsigned int)(vspan[uv] - 3) << 8);
    nuh[uv] = pack4h(Nu4[uv]);
    nvh[uv] = pack4h(Nv4[uv]);
}

// ---------- main: block = (chunk, b); whole batch in LDS; no inner barriers ----------
__global__ __launch_bounds__(TPB) void surfeval_r11_kernel(
    const uint2* __restrict__ ctrlP,
    const unsigned int* __restrict__ spk,
    const uint2* __restrict__ nuh,
    const uint2* __restrict__ nvh,
    float* __restrict__ out)
{
    __shared__ uint2 cl[MN];                 // 128 KB: this block's batch, half4/(m,n)

    const int bid  = blockIdx.x;             // (c&7) + 8*(b + 8*(c>>3))
    const int th   = bid >> 3;
    const int b    = th & 7;
    const int c    = (bid & 7) | ((th >> 3) << 3);
    const int tid  = threadIdx.x;

    // stage batch b: dense 128 KB copy from planar fp16
    const uint2* src = ctrlP + b * MN;
    #pragma unroll
    for (int i = 0; i < MN / TPB; ++i)       // 16 iters
        cl[i * TPB + tid] = src[i * TPB + tid];
    __syncthreads();

    const char* ldsb = (const char*)cl;

    #pragma unroll 1
    for (int it = 0; it < ITERS; ++it) {
        const int uv = c * UVPC + it * TPB + tid;   // wave: 64 consecutive uv

        const unsigned int sp = spk[uv];
        const int us3 = sp & 0xFF;
        const int vs3 = (sp >> 8) & 0xFF;
        const uint2 nupk = nuh[uv];
        const uint2 nvpk = nvh[uv];
        const float2 nu01 = __half22float2(*(const __half2*)(&nupk.x));
        const float2 nu23 = __half22float2(*(const __half2*)(&nupk.y));
        const float2 nv01 = __half22float2(*(const __half2*)(&nvpk.x));
        const float2 nv23 = __half22float2(*(const __half2*)(&nvpk.y));
        const float nuL[4] = {nu01.x, nu01.y, nu23.x, nu23.y};
        const float nvL[4] = {nv01.x, nv01.y, nv23.x, nv23.y};

        const int base = (us3 * ND + vs3) * 8;       // byte offset in LDS
        float ax = 0.f, ay = 0.f, az = 0.f, aw = 0.f;
        #pragma unroll
        for (int l = 0; l < 4; ++l) {
            #pragma unroll
            for (int r = 0; r < 4; ++r) {
                const uint2 h = *(const uint2*)(ldsb + base + l * (ND * 8) + r * 8);
                const float w = nuL[l] * nvL[r];
                const float2 xy = __half22float2(*(const __half2*)(&h.x));
                const float2 zw = __half22float2(*(const __half2*)(&h.y));
                ax = fmaf(w, xy.x, ax);
                ay = fmaf(w, xy.y, ay);
                az = fmaf(w, zw.x, az);
                aw = fmaf(w, zw.y, aw);
            }
        }
        const float inv = 1.0f / aw;
        float* o = out + ((size_t)b * UVN + uv) * 3; // dense 768 B per wave
        o[0] = ax * inv;
        o[1] = ay * inv;
        o[2] = az * inv;
    }
}

// ================= r9 fallback (verified 27.5 µs, needs 1 MB ws) =================
__global__ __launch_bounds__(256) void transpose_h_kernel(
    const float4* __restrict__ ctrl, ushort4* __restrict__ ctrlH)
{
    const int tid = blockIdx.x * blockDim.x + threadIdx.x;
    const int b   = tid & 7;
    const int mn  = tid >> 3;
    ctrlH[tid] = cvt4h(ctrl[b * MN + mn]);
}

__global__ __launch_bounds__(256) void surfeval_h2_kernel(
    const uint4* __restrict__ ctrlH4,
    const float4* __restrict__ Nu4,
    const float4* __restrict__ Nv4,
    const int* __restrict__ uspan,
    const int* __restrict__ vspan,
    float* __restrict__ out)
{
    __shared__ float rs[BD * 196];
    const int tidx = threadIdx.x;
    const int bp   = tidx & 3;
    const int uvL  = tidx >> 2;
    const int uv   = blockIdx.x * 64 + uvL;

    const int us3 = uspan[uv] - 3;
    const int vs3 = vspan[uv] - 3;
    const float4 nu = Nu4[uv];
    const float4 nv = Nv4[uv];
    const float nuL[4] = {nu.x, nu.y, nu.z, nu.w};
    const float nvL[4] = {nv.x, nv.y, nv.z, nv.w};

    const uint4* cp = ctrlH4 + ((size_t)(us3 * ND + vs3) * 4 + bp);
    uint4 c[4][4];
    #pragma unroll
    for (int l = 0; l < 4; ++l) {
        const uint4* row = cp + l * (ND * 4);
        #pragma unroll
        for (int r = 0; r < 4; ++r) c[l][r] = row[r * 4];
    }
    float ax0 = 0.f, ay0 = 0.f, az0 = 0.f, aw0 = 0.f;
    float ax1 = 0.f, ay1 = 0.f, az1 = 0.f, aw1 = 0.f;
    #pragma unroll
    for (int l = 0; l < 4; ++l) {
        #pragma unroll
        for (int r = 0; r < 4; ++r) {
            const float w = nuL[l] * nvL[r];
            const float2 a01 = __half22float2(*reinterpret_cast<const __half2*>(&c[l][r].x));
            const float2 a23 = __half22float2(*reinterpret_cast<const __half2*>(&c[l][r].y));
            const float2 b01 = __half22float2(*reinterpret_cast<const __half2*>(&c[l][r].z));
            const float2 b23 = __half22float2(*reinterpret_cast<const __half2*>(&c[l][r].w));
            ax0 = fmaf(w, a01.x, ax0); ay0 = fmaf(w, a01.y, ay0);
            az0 = fmaf(w, a23.x, az0); aw0 = fmaf(w, a23.y, aw0);
            ax1 = fmaf(w, b01.x, ax1); ay1 = fmaf(w, b01.y, ay1);
            az1 = fmaf(w, b23.x, az1); aw1 = fmaf(w, b23.y, aw1);
        }
    }
    const float inv0 = 1.0f / aw0;
    const float inv1 = 1.0f / aw1;
    const int b0 = 2 * bp;
    float* r0 = &rs[b0 * 196 + uvL * 3];
    r0[0] = ax0 * inv0; r0[1] = ay0 * inv0; r0[2] = az0 * inv0;
    float* r1 = &rs[(b0 + 1) * 196 + uvL * 3];
    r1[0] = ax1 * inv1; r1[1] = ay1 * inv1; r1[2] = az1 * inv1;
    __syncthreads();
    #pragma unroll
    for (int k = tidx; k < 384; k += 256) {
        const int bb = k / 48;
        const int j  = k - bb * 48;
        const float4 v = *reinterpret_cast<const float4*>(&rs[bb * 196 + j * 4]);
        float* dst = out + (size_t)bb * (UVN * 3) + (size_t)blockIdx.x * 192 + j * 4;
        *reinterpret_cast<float4*>(dst) = v;
    }
}

__global__ __launch_bounds__(256) void surfeval_naive_kernel(
    const float* __restrict__ ctrl, const float* __restrict__ Nu,
    const float* __restrict__ Nv, const int* __restrict__ uspan,
    const int* __restrict__ vspan, float* __restrict__ out)
{
    const int tid = blockIdx.x * blockDim.x + threadIdx.x;
    const int uv = tid & (UVN - 1);
    const int b  = tid >> 18;
    const int us = uspan[uv];
    const int vs = vspan[uv];
    const float4 nu = reinterpret_cast<const float4*>(Nu)[uv];
    const float4 nv = reinterpret_cast<const float4*>(Nv)[uv];
    const float nuL[4] = {nu.x, nu.y, nu.z, nu.w};
    const float nvL[4] = {nv.x, nv.y, nv.z, nv.w};
    const float4* cp = reinterpret_cast<const float4*>(ctrl)
                     + ((b * MD + (us - 3)) * ND + (vs - 3));
    float ax = 0.f, ay = 0.f, az = 0.f, aw = 0.f;
    #pragma unroll
    for (int l = 0; l < 4; ++l) {
        const float4* row = cp + l * ND;
        #pragma unroll
        for (int r = 0; r < 4; ++r) {
            const float w = nuL[l] * nvL[r];
            const float4 cc = row[r];
            ax = fmaf(w, cc.x, ax); ay = fmaf(w, cc.y, ay);
            az = fmaf(w, cc.z, az); aw = fmaf(w, cc.w, aw);
        }
    }
    const float inv = 1.0f / aw;
    float* o = out + (size_t)tid * 3;
    o[0] = ax * inv; o[1] = ay * inv; o[2] = az * inv;
}

extern "C" void kernel_launch(void* const* d_in, const int* in_sizes, int n_in,
                              void* d_out, int out_size, void* d_ws, size_t ws_size,
                              hipStream_t stream) {
    const float* ctrl  = (const float*)d_in[0];
    const float* Nu    = (const float*)d_in[1];
    const float* Nv    = (const float*)d_in[2];
    const int*   uspan = (const int*)d_in[3];
    const int*   vspan = (const int*)d_in[4];
    float* out = (float*)d_out;

    // ws layout: ctrlP 1MB | spk 1MB | nuh 2MB | nvh 2MB = 6MB
    const size_t oCtrl = 0;
    const size_t oSpk  = (size_t)1 << 20;
    const size_t oNuh  = (size_t)2 << 20;
    const size_t oNvh  = (size_t)4 << 20;
    const size_t wsReq = (size_t)6 << 20;

    if (ws_size >= wsReq) {
        char* ws = (char*)d_ws;
        uint2*        ctrlP = (uint2*)(ws + oCtrl);
        unsigned int* spkp  = (unsigned int*)(ws + oSpk);
        uint2*        nuhp  = (uint2*)(ws + oNuh);
        uint2*        nvhp  = (uint2*)(ws + oNvh);

        prep11_kernel<<<(BD * MN + UVN) / 256, 256, 0, stream>>>(
            (const float4*)ctrl, ctrlP, (const float4*)Nu, (const float4*)Nv,
            uspan, vspan, spkp, nuhp, nvhp);
        surfeval_r11_kernel<<<NCHUNK * BD, TPB, 0, stream>>>(
            ctrlP, spkp, nuhp, nvhp, out);
    } else if (ws_size >= (size_t)MN * BD * 8) {
        ushort4* ctrlH = (ushort4*)d_ws;
        transpose_h_kernel<<<(MN * BD) / 256, 256, 0, stream>>>(
            (const float4*)ctrl, ctrlH);
        surfeval_h2_kernel<<<UVN / 64, 256, 0, stream>>>(
            (const uint4*)ctrlH, (const float4*)Nu, (const float4*)Nv,
            uspan, vspan, out);
    } else {
        surfeval_naive_kernel<<<(BD * UVN) / 256, 256, 0, stream>>>(
            ctrl, Nu, Nv, uspan, vspan, out);
    }
}

// Round 12
// 24.459 us; speedup vs baseline: 1.2109x; 1.2071x over previous
//
#include <hip/hip_runtime.h>
#include <hip/hip_fp16.h>

// SurfEval: B=8, M=128, N=128, ctrl 4ch, P=Q=3, OUT=512
// ctrl_pts : (8,128,128,4) f32; Nu/Nv: (512,512,4) f32; spans: (512,512) i32 in [3,127]
// out : (8,512,512,3) f32 = sw[...,:3]/sw[...,3:]
//
// Round-12: single kernel. One batch's control net staged f32->fp16 into
// 128 KB LDS. Grid 256 = 32 uv-chunks x 8 batches, XCD-swizzled so the 8
// blocks sharing a chunk's streams sit on one XCD (L2 reuse). Inner math:
// packed fp16 FMA (v_pk_fma_f16) for the Nu-sum (kills the cvt wall),
// f32 for the Nv-sum and the rational divide. No barriers in the uv loop;
// all global accesses dense.

#define OUTD 512
#define UVN  (OUTD * OUTD)   // 262144
#define MD   128
#define ND   128
#define BD   8
#define MN   (MD * ND)       // 16384
#define TPB  1024
#define NCHUNK 32
#define UVPC (UVN / NCHUNK)  // 8192
#define ITERS (UVPC / TPB)   // 8

__device__ __forceinline__ uint2 pack4h(const float4 c) {
    __half2 h01 = __floats2half2_rn(c.x, c.y);
    __half2 h23 = __floats2half2_rn(c.z, c.w);
    uint2 u;
    u.x = *reinterpret_cast<unsigned int*>(&h01);
    u.y = *reinterpret_cast<unsigned int*>(&h23);
    return u;
}

__global__ __launch_bounds__(TPB) void surfeval_r12_kernel(
    const float4* __restrict__ ctrl,   // (b, m*n) float4
    const float4* __restrict__ Nu4,
    const float4* __restrict__ Nv4,
    const int* __restrict__ uspan,
    const int* __restrict__ vspan,
    float* __restrict__ out)
{
    __shared__ uint2 cl[MN];             // 128 KB: this block's batch, half4/(m,n)

    const int bid = blockIdx.x;          // bid = (c&7) + 8*(b + 8*(c>>3))
    const int b   = (bid >> 3) & 7;
    const int c   = (bid & 7) | ((bid >> 6) << 3);
    const int tid = threadIdx.x;

    // ---- stage batch b: 256 KB f32 -> 128 KB fp16 LDS (dense, conflict-free)
    const float4* cb = ctrl + b * MN;
    #pragma unroll
    for (int i = 0; i < MN / TPB; ++i) { // 16 iters
        const int idx = i * TPB + tid;
        cl[idx] = pack4h(cb[idx]);
    }
    __syncthreads();

    const char* ldsb = (const char*)cl;

    #pragma unroll 1
    for (int it = 0; it < ITERS; ++it) {
        const int uv = c * UVPC + it * TPB + tid;   // wave: 64 consecutive uv

        const int us3 = uspan[uv] - 3;
        const int vs3 = vspan[uv] - 3;
        const float4 nu = Nu4[uv];
        const float4 nv = Nv4[uv];

        // fp16 splats of Nu (for packed fma)
        __half2 nus[4];
        nus[0] = __float2half2_rn(nu.x);
        nus[1] = __float2half2_rn(nu.y);
        nus[2] = __float2half2_rn(nu.z);
        nus[3] = __float2half2_rn(nu.w);
        const float nvL[4] = {nv.x, nv.y, nv.z, nv.w};

        // inner Nu-sum in packed fp16: t[r] = sum_l Nu[l] * P[l][r]
        const int base = (us3 * ND + vs3) * 8;      // byte offset in LDS
        __half2 t01[4], t23[4];
        #pragma unroll
        for (int r = 0; r < 4; ++r) {
            t01[r] = __float2half2_rn(0.f);
            t23[r] = __float2half2_rn(0.f);
        }
        #pragma unroll
        for (int l = 0; l < 4; ++l) {
            #pragma unroll
            for (int r = 0; r < 4; ++r) {
                const uint2 h = *(const uint2*)(ldsb + base + l * (ND * 8) + r * 8);
                t01[r] = __hfma2(nus[l], *(const __half2*)(&h.x), t01[r]);
                t23[r] = __hfma2(nus[l], *(const __half2*)(&h.y), t23[r]);
            }
        }

        // outer Nv-sum in f32
        float ax = 0.f, ay = 0.f, az = 0.f, aw = 0.f;
        #pragma unroll
        for (int r = 0; r < 4; ++r) {
            const float2 xy = __half22float2(t01[r]);
            const float2 zw = __half22float2(t23[r]);
            ax = fmaf(nvL[r], xy.x, ax);
            ay = fmaf(nvL[r], xy.y, ay);
            az = fmaf(nvL[r], zw.x, az);
            aw = fmaf(nvL[r], zw.y, aw);
        }

        const float inv = 1.0f / aw;
        float* o = out + ((size_t)b * UVN + uv) * 3;   // dense 768 B per wave
        o[0] = ax * inv;
        o[1] = ay * inv;
        o[2] = az * inv;
    }
}

extern "C" void kernel_launch(void* const* d_in, const int* in_sizes, int n_in,
                              void* d_out, int out_size, void* d_ws, size_t ws_size,
                              hipStream_t stream) {
    const float* ctrl  = (const float*)d_in[0];
    const float* Nu    = (const float*)d_in[1];
    const float* Nv    = (const float*)d_in[2];
    const int*   uspan = (const int*)d_in[3];
    const int*   vspan = (const int*)d_in[4];
    float* out = (float*)d_out;

    surfeval_r12_kernel<<<NCHUNK * BD, TPB, 0, stream>>>(
        (const float4*)ctrl, (const float4*)Nu, (const float4*)Nv,
        uspan, vspan, out);
}